// Round 15
// baseline (1018.366 us; speedup 1.0000x reference)
//
#include <hip/hip_runtime.h>

// ---------------------------------------------------------------------------
// SubModel_22016002359901: 3x GCN(2 conv) + FC heads, N=100000, F=128, E=1.6M
// Round 15: round-14 base (943us) +
//   (1) csr_bucket with 512 threads (halves per-block serial phase iters),
//   (2) gather_bf 12-deep ILP (~50 VGPR, under the 64-VGPR occupancy cliff).
// Everything else byte-identical to round 14.
// ---------------------------------------------------------------------------

typedef short bf16x8 __attribute__((ext_vector_type(8)));
typedef float f32x4 __attribute__((ext_vector_type(4)));

#define BSHIFT 8                 // 256 dst nodes per bucket
#define NBUCK_MAX 400
#define BCAP 6144                // mean 4096 @ E=1.6M, sigma ~64 -> 32 sigma headroom
#define WDSCALE 8388608.f        // 2^23 fixed-point for weighted degree

static __device__ __forceinline__ float frelu(float x) { return x > 0.f ? x : 0.f; }

static __device__ __forceinline__ unsigned short f2bf(float f) {
    unsigned int u = __float_as_uint(f);
    u += 0x7fffu + ((u >> 16) & 1u);           // RNE
    return (unsigned short)(u >> 16);
}
static __device__ __forceinline__ float bflo(unsigned int u) {
    return __uint_as_float(u << 16);
}
static __device__ __forceinline__ float bfhi(unsigned int u) {
    return __uint_as_float(u & 0xffff0000u);
}

// ---------------- conversion kernels ----------------
__global__ void xconv(const float* __restrict__ src, unsigned short* __restrict__ dst, int n4) {
    int i = blockIdx.x * 256 + threadIdx.x;
    if (i >= n4) return;
    float4 v = *(const float4*)(src + (size_t)i * 4);
    ushort4 o = {f2bf(v.x), f2bf(v.y), f2bf(v.z), f2bf(v.w)};
    *(ushort4*)(dst + (size_t)i * 4) = o;
}

// batched transpose+convert for all 12 weight matrices (K all pow2)
struct WSegs {
    const float* src[13];
    unsigned short* dst[13];
    int beg[14];
    int ksh[13];
    int M[13];
};

__global__ void wtrans_all(WSegs segs, int total) {
    int idx = blockIdx.x * 256 + threadIdx.x;
    if (idx >= total) return;
    int s = 0;
#pragma unroll
    for (int i = 1; i < 13; ++i) s += (idx >= segs.beg[i]);
    int li = idx - segs.beg[s];
    int ksh = segs.ksh[s];
    int m = li >> ksh;
    int k = li & ((1 << ksh) - 1);
    segs.dst[s][li] = f2bf(segs.src[s][(size_t)k * segs.M[s] + m]);
}

__global__ void zero_small(int* __restrict__ p, int n) {
    int i = blockIdx.x * 256 + threadIdx.x;
    if (i < n) p[i] = 0;
}

// ---------------- bucketed edge partition (wave-private histograms) ----------
__global__ __launch_bounds__(256) void part_k(
    const int* __restrict__ src, const int* __restrict__ dst,
    const float* __restrict__ ew, int* __restrict__ gcur,
    int2* __restrict__ part, int nE, int nbuck) {
    __shared__ int lh[4][NBUCK_MAX];
    __shared__ int gb[4][NBUCK_MAX];
    const int tid = threadIdx.x;
    const int w = tid >> 6;
    for (int t = tid; t < 4 * NBUCK_MAX; t += 256) ((int*)lh)[t] = 0;
    __syncthreads();
    const int e0 = blockIdx.x * 4096;
    int rk[16], bk[16];
#pragma unroll
    for (int j = 0; j < 16; ++j) {
        int e = e0 + j * 256 + tid;
        rk[j] = -1;
        if (e < nE) {
            int b = dst[e] >> BSHIFT;
            bk[j] = b;
            rk[j] = atomicAdd(&lh[w][b], 1);
        }
    }
    __syncthreads();
    for (int t = tid; t < nbuck; t += 256) {
        int c0 = lh[0][t], c1 = lh[1][t], c2 = lh[2][t], c3 = lh[3][t];
        int tot = c0 + c1 + c2 + c3;
        int base = tot ? atomicAdd(&gcur[t], tot) : 0;
        gb[0][t] = base;
        gb[1][t] = base + c0;
        gb[2][t] = base + c0 + c1;
        gb[3][t] = base + c0 + c1 + c2;
    }
    __syncthreads();
#pragma unroll
    for (int j = 0; j < 16; ++j) {
        int e = e0 + j * 256 + tid;
        if (e >= nE) continue;
        int b = bk[j];
        int slot = gb[w][b] + rk[j];
        if (slot >= 0 && slot < BCAP) {
            int s = src[e];
            int dl = dst[e] & ((1 << BSHIFT) - 1);
            part[(size_t)b * BCAP + slot] = make_int2(s | (dl << 17), __float_as_int(ew[e]));
        }
    }
}

// exclusive scan of clamped bucket counts -> bbase; rp[n] = total
__global__ void scanB(const int* __restrict__ gcur, int* __restrict__ bbase,
                      int* __restrict__ rp, int n, int nbuck) {
    __shared__ int s[512];
    int t = threadIdx.x;
    int c = (t < nbuck) ? gcur[t] : 0;
    if (c > BCAP) c = BCAP;
    s[t] = c;
    __syncthreads();
#pragma unroll
    for (int off = 1; off < 512; off <<= 1) {
        int x = (t >= off) ? s[t - off] : 0;
        __syncthreads();
        s[t] += x;
        __syncthreads();
    }
    if (t < nbuck) bbase[t] = s[t] - c;
    if (t == nbuck - 1) rp[n] = s[t];
}

// csr_bucket (512 threads): LDS counting sort by dstlocal; fixed-point
// weighted degree fused into the scatter pass; rp per node.
__global__ __launch_bounds__(512) void csr_bucket(
    const int2* __restrict__ part, const int* __restrict__ gcur,
    const int* __restrict__ bbase, int2* __restrict__ ev,
    int* __restrict__ rp, float* __restrict__ dinv, int n) {
    __shared__ int hist[256];
    __shared__ int cur[256];
    __shared__ int wd[256];
    const int b = blockIdx.x;
    const int t = threadIdx.x;          // 0..511
    int cnt = gcur[b];
    if (cnt > BCAP) cnt = BCAP;
    const int gbase = bbase[b];
    const int2* pb = part + (size_t)b * BCAP;

    if (t < 256) { hist[t] = 0; wd[t] = 0; }
    __syncthreads();
    for (int i = t; i < cnt; i += 512)
        atomicAdd(&hist[(pb[i].x >> 17) & 255], 1);
    __syncthreads();
    int myh = (t < 256) ? hist[t] : 0;
#pragma unroll
    for (int off = 1; off < 256; off <<= 1) {
        int x = (t < 256 && t >= off) ? hist[t - off] : 0;
        __syncthreads();
        if (t < 256) hist[t] += x;
        __syncthreads();
    }
    int excl = (t < 256) ? (hist[t] - myh) : 0;
    if (t < 256) cur[t] = excl;
    __syncthreads();
    for (int i = t; i < cnt; i += 512) {
        int2 p = pb[i];
        int dl = (p.x >> 17) & 255;
        int pos = atomicAdd(&cur[dl], 1);
        ev[(size_t)gbase + pos] = make_int2(p.x & 0x1FFFF, p.y);
        atomicAdd(&wd[dl], (int)(__int_as_float(p.y) * WDSCALE + 0.5f));
    }
    __syncthreads();
    if (t < 256) {
        int g = (b << BSHIFT) + t;
        if (g < n) {
            dinv[g] = rsqrtf(1.f + (float)wd[t] * (1.f / WDSCALE));
            rp[g] = gbase + excl;
        }
    }
}

// gather: one wave per node, 12-deep ILP.
// aggr = relu( dinv[n]*sum(dinv[src]*ew*h[src]) + dinv[n]^2*h[n] + bias )
__global__ __launch_bounds__(256) void gather_bf(
    const int* __restrict__ rp, const int2* __restrict__ ev,
    const unsigned short* __restrict__ h,
    const float* __restrict__ dinv, const float* __restrict__ bias,
    unsigned short* __restrict__ aggr, int n) {
    int node = (int)(((size_t)blockIdx.x * 256 + threadIdx.x) >> 6);
    if (node >= n) return;
    int lane = threadIdx.x & 63;
    float di = dinv[node];
    float sl = di * di;
    unsigned int hu = *(const unsigned int*)(h + (size_t)node * 128 + lane * 2);
    float2 bv = *(const float2*)(bias + lane * 2);
    float ax[4] = {0.f, 0.f, 0.f, 0.f};
    float ay[4] = {0.f, 0.f, 0.f, 0.f};
    const int beg = rp[node], end = rp[node + 1];
    int i = beg;
    for (; i + 11 < end; i += 12) {
        int2 e[12];
#pragma unroll
        for (int j = 0; j < 12; ++j) e[j] = ev[i + j];
        float nm[12];
#pragma unroll
        for (int j = 0; j < 12; ++j) nm[j] = dinv[e[j].x] * __int_as_float(e[j].y);
        unsigned int u[12];
#pragma unroll
        for (int j = 0; j < 12; ++j)
            u[j] = *(const unsigned int*)(h + (size_t)e[j].x * 128 + lane * 2);
#pragma unroll
        for (int j = 0; j < 12; ++j) {
            ax[j & 3] += nm[j] * bflo(u[j]);
            ay[j & 3] += nm[j] * bfhi(u[j]);
        }
    }
    for (; i + 3 < end; i += 4) {
        int2 e[4];
#pragma unroll
        for (int j = 0; j < 4; ++j) e[j] = ev[i + j];
        float nm[4];
#pragma unroll
        for (int j = 0; j < 4; ++j) nm[j] = dinv[e[j].x] * __int_as_float(e[j].y);
        unsigned int u[4];
#pragma unroll
        for (int j = 0; j < 4; ++j)
            u[j] = *(const unsigned int*)(h + (size_t)e[j].x * 128 + lane * 2);
#pragma unroll
        for (int j = 0; j < 4; ++j) {
            ax[j] += nm[j] * bflo(u[j]);
            ay[j] += nm[j] * bfhi(u[j]);
        }
    }
    for (; i < end; ++i) {
        int2 e0 = ev[i];
        float n0 = dinv[e0.x] * __int_as_float(e0.y);
        unsigned int u0 = *(const unsigned int*)(h + (size_t)e0.x * 128 + lane * 2);
        ax[0] += n0 * bflo(u0); ay[0] += n0 * bfhi(u0);
    }
    float ox = frelu(di * ((ax[0] + ax[1]) + (ax[2] + ax[3])) + sl * bflo(hu) + bv.x);
    float oy = frelu(di * ((ay[0] + ay[1]) + (ay[2] + ay[3])) + sl * bfhi(hu) + bv.y);
    unsigned int o = (unsigned int)f2bf(ox) | ((unsigned int)f2bf(oy) << 16);
    *(unsigned int*)(aggr + (size_t)node * 128 + lane * 2) = o;
}

// ---------------- conv GEMM ----------------
template<int K, int BN, int RELU, int EPI>
__global__ __launch_bounds__(256, 2) void gemm_bf(
    const unsigned short* __restrict__ A, const unsigned short* __restrict__ Wt,
    const float* __restrict__ bias, void* __restrict__ Cout,
    int M, int nrows, float* __restrict__ xs) {
    constexpr int BM = 128, BK = 64;
    constexpr int WN = BN / 2;
    constexpr int NF = WN / 16;
    static_assert(BN == 64 || BN == 128, "BN");
    __shared__ unsigned short As[BM][BK + 8];
    __shared__ unsigned short Bs[BN][BK + 8];

    const int tid  = threadIdx.x;
    const int wid  = tid >> 6;
    const int lane = tid & 63;
    const int wm   = (wid >> 1) * 64;
    const int wn   = (wid & 1) * WN;
    const int row0 = blockIdx.x * BM;
    const int col0 = blockIdx.y * BN;
    const int lr   = lane & 15;
    const int lk   = (lane >> 4) * 8;

    f32x4 acc[4][NF] = {};

    for (int k0 = 0; k0 < K; k0 += BK) {
#pragma unroll
        for (int it = 0; it < 4; ++it) {
            int f = tid + it * 256;
            int r = f >> 3, g = f & 7;
            int grow = row0 + r;
            if (grow >= nrows) grow = nrows - 1;
            bf16x8 v = *(const bf16x8*)(A + (size_t)grow * K + k0 + g * 8);
            *(bf16x8*)&As[r][g * 8] = v;
        }
#pragma unroll
        for (int it = 0; it < BN / 32; ++it) {
            int f = tid + it * 256;
            int nidx = f >> 3, g = f & 7;
            bf16x8 v = *(const bf16x8*)(Wt + (size_t)(col0 + nidx) * K + k0 + g * 8);
            *(bf16x8*)&Bs[nidx][g * 8] = v;
        }
        __syncthreads();
#pragma unroll
        for (int kk = 0; kk < 2; ++kk) {
            bf16x8 af[4], bfv[NF];
#pragma unroll
            for (int mi = 0; mi < 4; ++mi)
                af[mi] = *(const bf16x8*)&As[wm + 16 * mi + lr][kk * 32 + lk];
#pragma unroll
            for (int ni = 0; ni < NF; ++ni)
                bfv[ni] = *(const bf16x8*)&Bs[wn + 16 * ni + lr][kk * 32 + lk];
#pragma unroll
            for (int mi = 0; mi < 4; ++mi)
#pragma unroll
                for (int ni = 0; ni < NF; ++ni)
                    acc[mi][ni] = __builtin_amdgcn_mfma_f32_16x16x32_bf16(
                        af[mi], bfv[ni], acc[mi][ni], 0, 0, 0);
        }
        __syncthreads();
    }

    const int dr0 = (lane >> 4) * 4;
#pragma unroll
    for (int ni = 0; ni < NF; ++ni) {
        int col = col0 + wn + 16 * ni + lr;
        float bv = bias ? bias[col] : 0.f;
#pragma unroll
        for (int mi = 0; mi < 4; ++mi) {
#pragma unroll
            for (int r = 0; r < 4; ++r) {
                int grow = row0 + wm + 16 * mi + dr0 + r;
                if (grow >= nrows) continue;
                float v = acc[mi][ni][r] + bv;
                if (RELU) v = frelu(v);
                if (EPI == 0) {
                    ((unsigned short*)Cout)[(size_t)grow * M + col] = f2bf(v);
                } else {
                    ((float*)Cout)[(size_t)grow * M + col] = v;
                    if (EPI == 2) xs[(size_t)grow * 64 + col] += v;
                }
            }
        }
    }
}

// ---------------- fused fc chain: in[128] ->256 ->128 ->64 ----------------
template<int EPI>
__global__ __launch_bounds__(256, 2) void fc_chain(
    const unsigned short* __restrict__ A,
    const unsigned short* __restrict__ W1t, const float* __restrict__ b1,
    const unsigned short* __restrict__ W2t, const float* __restrict__ b2,
    const unsigned short* __restrict__ W3t, const float* __restrict__ b3,
    float* __restrict__ Cout, int nrows, float* __restrict__ xs) {
    __shared__ unsigned short Ain[128 * 136];
    __shared__ unsigned short T1q[128 * 72];
    __shared__ unsigned short Bst[128 * 72];

    const int tid  = threadIdx.x;
    const int wid  = tid >> 6;
    const int lane = tid & 63;
    const int wm   = (wid >> 1) * 64;
    const int wnH  = (wid & 1) * 32;
    const int wnF  = (wid & 1) * 64;
    const int row0 = blockIdx.x * 128;
    const int lr   = lane & 15;
    const int lk   = (lane >> 4) * 8;
    const int dr0  = (lane >> 4) * 4;

#pragma unroll
    for (int it = 0; it < 8; ++it) {
        int f = tid + it * 256;
        int r = f >> 4, g = f & 15;
        int grow = row0 + r; if (grow >= nrows) grow = nrows - 1;
        *(bf16x8*)&Ain[r * 136 + g * 8] =
            *(const bf16x8*)(A + (size_t)grow * 128 + g * 8);
    }

    f32x4 acc2[4][4] = {};

    for (int q = 0; q < 4; ++q) {
        __syncthreads();
#pragma unroll
        for (int it = 0; it < 4; ++it) {
            int f = tid + it * 256;
            int r = f >> 4, g = f & 15;
            *(bf16x8*)&Bst[r * 136 + g * 8] =
                *(const bf16x8*)(W1t + (size_t)(q * 64 + r) * 128 + g * 8);
        }
        __syncthreads();
        f32x4 acc1[4][2] = {};
#pragma unroll
        for (int kk = 0; kk < 4; ++kk) {
            bf16x8 af[4], bw[2];
#pragma unroll
            for (int mi = 0; mi < 4; ++mi)
                af[mi] = *(const bf16x8*)&Ain[(wm + 16 * mi + lr) * 136 + kk * 32 + lk];
#pragma unroll
            for (int ni = 0; ni < 2; ++ni)
                bw[ni] = *(const bf16x8*)&Bst[(wnH + 16 * ni + lr) * 136 + kk * 32 + lk];
#pragma unroll
            for (int mi = 0; mi < 4; ++mi)
#pragma unroll
                for (int ni = 0; ni < 2; ++ni)
                    acc1[mi][ni] = __builtin_amdgcn_mfma_f32_16x16x32_bf16(
                        af[mi], bw[ni], acc1[mi][ni], 0, 0, 0);
        }
        __syncthreads();
#pragma unroll
        for (int ni = 0; ni < 2; ++ni) {
            float bv = b1[q * 64 + wnH + 16 * ni + lr];
#pragma unroll
            for (int mi = 0; mi < 4; ++mi)
#pragma unroll
                for (int r = 0; r < 4; ++r)
                    T1q[(wm + 16 * mi + dr0 + r) * 72 + wnH + 16 * ni + lr] =
                        f2bf(frelu(acc1[mi][ni][r] + bv));
        }
#pragma unroll
        for (int it = 0; it < 4; ++it) {
            int f = tid + it * 256;
            int r = f >> 3, g = f & 7;
            *(bf16x8*)&Bst[r * 72 + g * 8] =
                *(const bf16x8*)(W2t + (size_t)r * 256 + q * 64 + g * 8);
        }
        __syncthreads();
#pragma unroll
        for (int kk = 0; kk < 2; ++kk) {
            bf16x8 af[4], bw[4];
#pragma unroll
            for (int mi = 0; mi < 4; ++mi)
                af[mi] = *(const bf16x8*)&T1q[(wm + 16 * mi + lr) * 72 + kk * 32 + lk];
#pragma unroll
            for (int ni = 0; ni < 4; ++ni)
                bw[ni] = *(const bf16x8*)&Bst[(wnF + 16 * ni + lr) * 72 + kk * 32 + lk];
#pragma unroll
            for (int mi = 0; mi < 4; ++mi)
#pragma unroll
                for (int ni = 0; ni < 4; ++ni)
                    acc2[mi][ni] = __builtin_amdgcn_mfma_f32_16x16x32_bf16(
                        af[mi], bw[ni], acc2[mi][ni], 0, 0, 0);
        }
    }
    __syncthreads();
#pragma unroll
    for (int ni = 0; ni < 4; ++ni) {
        float bv = b2[wnF + 16 * ni + lr];
#pragma unroll
        for (int mi = 0; mi < 4; ++mi)
#pragma unroll
            for (int r = 0; r < 4; ++r)
                Ain[(wm + 16 * mi + dr0 + r) * 136 + wnF + 16 * ni + lr] =
                    f2bf(frelu(acc2[mi][ni][r] + bv));
    }
#pragma unroll
    for (int it = 0; it < 4; ++it) {
        int f = tid + it * 256;
        int r = f >> 4, g = f & 15;
        *(bf16x8*)&Bst[r * 136 + g * 8] =
            *(const bf16x8*)(W3t + (size_t)r * 128 + g * 8);
    }
    __syncthreads();
    f32x4 acc3[4][2] = {};
#pragma unroll
    for (int kk = 0; kk < 4; ++kk) {
        bf16x8 af[4], bw[2];
#pragma unroll
        for (int mi = 0; mi < 4; ++mi)
            af[mi] = *(const bf16x8*)&Ain[(wm + 16 * mi + lr) * 136 + kk * 32 + lk];
#pragma unroll
        for (int ni = 0; ni < 2; ++ni)
            bw[ni] = *(const bf16x8*)&Bst[(wnH + 16 * ni + lr) * 136 + kk * 32 + lk];
#pragma unroll
        for (int mi = 0; mi < 4; ++mi)
#pragma unroll
            for (int ni = 0; ni < 2; ++ni)
                acc3[mi][ni] = __builtin_amdgcn_mfma_f32_16x16x32_bf16(
                    af[mi], bw[ni], acc3[mi][ni], 0, 0, 0);
    }
#pragma unroll
    for (int ni = 0; ni < 2; ++ni) {
        int col = wnH + 16 * ni + lr;
        float bv = b3[col];
#pragma unroll
        for (int mi = 0; mi < 4; ++mi)
#pragma unroll
            for (int r = 0; r < 4; ++r) {
                int grow = row0 + wm + 16 * mi + dr0 + r;
                if (grow >= nrows) continue;
                float v = frelu(acc3[mi][ni][r] + bv);
                Cout[(size_t)grow * 64 + col] = v;
                if (EPI == 2) xs[(size_t)grow * 64 + col] += v;
            }
    }
}

// ---------------------------------------------------------------------------
extern "C" void kernel_launch(void* const* d_in, const int* in_sizes, int n_in,
                              void* d_out, int out_size, void* d_ws, size_t ws_size,
                              hipStream_t stream) {
    (void)n_in; (void)out_size; (void)ws_size;
    const float* X = (const float*)d_in[0];
    const int N = in_sizes[0] / 128;

    const float* fc1_b1 = (const float*)d_in[20];
    const float* fc1_b2 = (const float*)d_in[22];
    const float* fc1_b3 = (const float*)d_in[24];
    const float* fc2_b1 = (const float*)d_in[26];
    const float* fc2_b2 = (const float*)d_in[28];
    const float* fc2_b3 = (const float*)d_in[30];

    float* out = (float*)d_out;
    float* Xs  = out;  // slot 0

    // ---- workspace layout ----
    char* base = (char*)d_ws;
    const size_t Npad = (((size_t)N + 255) / 256) * 256;
    float*          dinv  = (float*)base;                 base += Npad * 4;
    unsigned short* Xbf   = (unsigned short*)base;        base += (size_t)N * 128 * 2;
    unsigned short* t1bf  = (unsigned short*)base;        base += (size_t)N * 256 * 2;  // CSR arena
    unsigned short* t2bf  = (unsigned short*)base;        base += (size_t)N * 128 * 2;
    unsigned short* aggbf = (unsigned short*)base;        base += (size_t)N * 128 * 2;
    unsigned short* wtbuf = (unsigned short*)base;        base += 245760 * 2;
    int*            gcur3 = (int*)base;                   base += 3 * NBUCK_MAX * 4;
    int*            bbase = (int*)base;                   base += NBUCK_MAX * 4;

    unsigned short* fc1w1t = wtbuf;
    unsigned short* fc1w2t = fc1w1t + 32768;
    unsigned short* fc1w3t = fc1w2t + 32768;
    unsigned short* fc2w1t = fc1w3t + 8192;
    unsigned short* fc2w2t = fc2w1t + 32768;
    unsigned short* fc2w3t = fc2w2t + 32768;
    unsigned short* gwt    = fc2w3t + 8192;        // 6 x 16384

    const dim3 blk(256);
    const int GR = (N + 127) / 128;
    const int NBUCK = (N + 255) >> 8;     // 391 for N=100000
    const int GWB = (int)(((size_t)N * 64 + 255) / 256);

    // ---- one-time conversions (batched) ----
    xconv<<<(N * 32 + 255) / 256, blk, 0, stream>>>(X, Xbf, N * 32);
    {
        WSegs segs;
        const float* srcs[13] = {
            (const float*)d_in[19], (const float*)d_in[21], (const float*)d_in[23],
            (const float*)d_in[25], (const float*)d_in[27], (const float*)d_in[29],
            (const float*)d_in[3],  (const float*)d_in[5],
            (const float*)d_in[9],  (const float*)d_in[11],
            (const float*)d_in[15], (const float*)d_in[17]
        };
        unsigned short* dsts[13] = {
            fc1w1t, fc1w2t, fc1w3t, fc2w1t, fc2w2t, fc2w3t,
            gwt, gwt + 16384, gwt + 32768, gwt + 49152, gwt + 65536, gwt + 81920
        };
        int ksh[13] = {7, 8, 7, 7, 8, 7, 7, 7, 7, 7, 7, 7};
        int Ms[13]  = {256, 128, 64, 256, 128, 64, 128, 128, 128, 128, 128, 128};
        int sz[13]  = {32768, 32768, 8192, 32768, 32768, 8192,
                       16384, 16384, 16384, 16384, 16384, 16384};
        int acc = 0;
        for (int i = 0; i < 12; ++i) {
            segs.src[i] = srcs[i]; segs.dst[i] = dsts[i];
            segs.ksh[i] = ksh[i];  segs.M[i] = Ms[i];
            segs.beg[i] = acc;     acc += sz[i];
        }
        segs.src[12] = srcs[11]; segs.dst[12] = dsts[11];
        segs.ksh[12] = 7; segs.M[12] = 128;
        segs.beg[12] = acc; segs.beg[13] = acc;
        wtrans_all<<<(acc + 255) / 256, blk, 0, stream>>>(segs, acc);
    }
    zero_small<<<(3 * NBUCK_MAX + 255) / 256, blk, 0, stream>>>(gcur3, 3 * NBUCK_MAX);

    // ---- X0 = fc1(X) -> Xs (fused chain) ----
    fc_chain<1><<<GR, blk, 0, stream>>>(Xbf, fc1w1t, fc1_b1, fc1w2t, fc1_b2,
                                        fc1w3t, fc1_b3, Xs, N, nullptr);

    // ---- graphs ----
    for (int g = 0; g < 3; ++g) {
        const int*   ei  = (const int*)d_in[1 + 6 * g];
        const int    E   = in_sizes[1 + 6 * g] / 2;
        const int*   srp = ei;
        const int*   dsp = ei + E;
        const float* ew  = (const float*)d_in[2 + 6 * g];
        const float* b1  = (const float*)d_in[4 + 6 * g];
        const float* b2  = (const float*)d_in[6 + 6 * g];
        unsigned short* w1t = gwt + (size_t)g * 32768;
        unsigned short* w2t = w1t + 16384;
        int* gcur = gcur3 + g * NBUCK_MAX;

        // CSR arena aliases t1bf
        int2* part  = (int2*)t1bf;                        // NBUCK * BCAP
        int2* ev    = part + (size_t)NBUCK * BCAP;        // E
        int*  rpn   = (int*)(ev + E);                     // N+1

        part_k<<<(E + 4095) / 4096, blk, 0, stream>>>(srp, dsp, ew, gcur, part, E, NBUCK);
        scanB<<<1, 512, 0, stream>>>(gcur, bbase, rpn, N, NBUCK);
        csr_bucket<<<NBUCK, 512, 0, stream>>>(part, gcur, bbase, ev, rpn, dinv, N);

        // conv1 + conv2
        gemm_bf<128, 128, 0, 0><<<dim3(GR, 1), blk, 0, stream>>>(Xbf, w1t, nullptr, t2bf, 128, N, nullptr);
        gather_bf<<<GWB, blk, 0, stream>>>(rpn, ev, t2bf, dinv, b1, aggbf, N);
        gemm_bf<128, 128, 0, 0><<<dim3(GR, 1), blk, 0, stream>>>(aggbf, w2t, nullptr, t2bf, 128, N, nullptr);
        gather_bf<<<GWB, blk, 0, stream>>>(rpn, ev, t2bf, dinv, b2, aggbf, N);

        // fc2 head (fused chain, xs accumulate)
        fc_chain<2><<<GR, blk, 0, stream>>>(aggbf, fc2w1t, fc2_b1, fc2w2t, fc2_b2,
                                            fc2w3t, fc2_b3,
                                            out + (size_t)(1 + g) * N * 64, N, Xs);
    }
}

// Round 16
// 932.981 us; speedup vs baseline: 1.0915x; 1.0915x over previous
//
#include <hip/hip_runtime.h>

// ---------------------------------------------------------------------------
// SubModel_22016002359901: 3x GCN(2 conv) + FC heads, N=100000, F=128, E=1.6M
// Round 16: revert gather_bf to the round-14 8-deep ILP version (12-deep cost
// occupancy 60->52%, gather 76->90us -- 8-deep is the ILP/TLP sweet spot).
// Keep csr_bucket@512 from round 15 (neutral-to-positive). Everything else
// identical to round 14 (943us best).
// ---------------------------------------------------------------------------

typedef short bf16x8 __attribute__((ext_vector_type(8)));
typedef float f32x4 __attribute__((ext_vector_type(4)));

#define BSHIFT 8                 // 256 dst nodes per bucket
#define NBUCK_MAX 400
#define BCAP 6144                // mean 4096 @ E=1.6M, sigma ~64 -> 32 sigma headroom
#define WDSCALE 8388608.f        // 2^23 fixed-point for weighted degree

static __device__ __forceinline__ float frelu(float x) { return x > 0.f ? x : 0.f; }

static __device__ __forceinline__ unsigned short f2bf(float f) {
    unsigned int u = __float_as_uint(f);
    u += 0x7fffu + ((u >> 16) & 1u);           // RNE
    return (unsigned short)(u >> 16);
}
static __device__ __forceinline__ float bflo(unsigned int u) {
    return __uint_as_float(u << 16);
}
static __device__ __forceinline__ float bfhi(unsigned int u) {
    return __uint_as_float(u & 0xffff0000u);
}

// ---------------- conversion kernels ----------------
__global__ void xconv(const float* __restrict__ src, unsigned short* __restrict__ dst, int n4) {
    int i = blockIdx.x * 256 + threadIdx.x;
    if (i >= n4) return;
    float4 v = *(const float4*)(src + (size_t)i * 4);
    ushort4 o = {f2bf(v.x), f2bf(v.y), f2bf(v.z), f2bf(v.w)};
    *(ushort4*)(dst + (size_t)i * 4) = o;
}

// batched transpose+convert for all 12 weight matrices (K all pow2)
struct WSegs {
    const float* src[13];
    unsigned short* dst[13];
    int beg[14];
    int ksh[13];
    int M[13];
};

__global__ void wtrans_all(WSegs segs, int total) {
    int idx = blockIdx.x * 256 + threadIdx.x;
    if (idx >= total) return;
    int s = 0;
#pragma unroll
    for (int i = 1; i < 13; ++i) s += (idx >= segs.beg[i]);
    int li = idx - segs.beg[s];
    int ksh = segs.ksh[s];
    int m = li >> ksh;
    int k = li & ((1 << ksh) - 1);
    segs.dst[s][li] = f2bf(segs.src[s][(size_t)k * segs.M[s] + m]);
}

__global__ void zero_small(int* __restrict__ p, int n) {
    int i = blockIdx.x * 256 + threadIdx.x;
    if (i < n) p[i] = 0;
}

// ---------------- bucketed edge partition (wave-private histograms) ----------
__global__ __launch_bounds__(256) void part_k(
    const int* __restrict__ src, const int* __restrict__ dst,
    const float* __restrict__ ew, int* __restrict__ gcur,
    int2* __restrict__ part, int nE, int nbuck) {
    __shared__ int lh[4][NBUCK_MAX];
    __shared__ int gb[4][NBUCK_MAX];
    const int tid = threadIdx.x;
    const int w = tid >> 6;
    for (int t = tid; t < 4 * NBUCK_MAX; t += 256) ((int*)lh)[t] = 0;
    __syncthreads();
    const int e0 = blockIdx.x * 4096;
    int rk[16], bk[16];
#pragma unroll
    for (int j = 0; j < 16; ++j) {
        int e = e0 + j * 256 + tid;
        rk[j] = -1;
        if (e < nE) {
            int b = dst[e] >> BSHIFT;
            bk[j] = b;
            rk[j] = atomicAdd(&lh[w][b], 1);
        }
    }
    __syncthreads();
    for (int t = tid; t < nbuck; t += 256) {
        int c0 = lh[0][t], c1 = lh[1][t], c2 = lh[2][t], c3 = lh[3][t];
        int tot = c0 + c1 + c2 + c3;
        int base = tot ? atomicAdd(&gcur[t], tot) : 0;
        gb[0][t] = base;
        gb[1][t] = base + c0;
        gb[2][t] = base + c0 + c1;
        gb[3][t] = base + c0 + c1 + c2;
    }
    __syncthreads();
#pragma unroll
    for (int j = 0; j < 16; ++j) {
        int e = e0 + j * 256 + tid;
        if (e >= nE) continue;
        int b = bk[j];
        int slot = gb[w][b] + rk[j];
        if (slot >= 0 && slot < BCAP) {
            int s = src[e];
            int dl = dst[e] & ((1 << BSHIFT) - 1);
            part[(size_t)b * BCAP + slot] = make_int2(s | (dl << 17), __float_as_int(ew[e]));
        }
    }
}

// exclusive scan of clamped bucket counts -> bbase; rp[n] = total
__global__ void scanB(const int* __restrict__ gcur, int* __restrict__ bbase,
                      int* __restrict__ rp, int n, int nbuck) {
    __shared__ int s[512];
    int t = threadIdx.x;
    int c = (t < nbuck) ? gcur[t] : 0;
    if (c > BCAP) c = BCAP;
    s[t] = c;
    __syncthreads();
#pragma unroll
    for (int off = 1; off < 512; off <<= 1) {
        int x = (t >= off) ? s[t - off] : 0;
        __syncthreads();
        s[t] += x;
        __syncthreads();
    }
    if (t < nbuck) bbase[t] = s[t] - c;
    if (t == nbuck - 1) rp[n] = s[t];
}

// csr_bucket (512 threads): LDS counting sort by dstlocal; fixed-point
// weighted degree fused into the scatter pass; rp per node.
__global__ __launch_bounds__(512) void csr_bucket(
    const int2* __restrict__ part, const int* __restrict__ gcur,
    const int* __restrict__ bbase, int2* __restrict__ ev,
    int* __restrict__ rp, float* __restrict__ dinv, int n) {
    __shared__ int hist[256];
    __shared__ int cur[256];
    __shared__ int wd[256];
    const int b = blockIdx.x;
    const int t = threadIdx.x;          // 0..511
    int cnt = gcur[b];
    if (cnt > BCAP) cnt = BCAP;
    const int gbase = bbase[b];
    const int2* pb = part + (size_t)b * BCAP;

    if (t < 256) { hist[t] = 0; wd[t] = 0; }
    __syncthreads();
    for (int i = t; i < cnt; i += 512)
        atomicAdd(&hist[(pb[i].x >> 17) & 255], 1);
    __syncthreads();
    int myh = (t < 256) ? hist[t] : 0;
#pragma unroll
    for (int off = 1; off < 256; off <<= 1) {
        int x = (t < 256 && t >= off) ? hist[t - off] : 0;
        __syncthreads();
        if (t < 256) hist[t] += x;
        __syncthreads();
    }
    int excl = (t < 256) ? (hist[t] - myh) : 0;
    if (t < 256) cur[t] = excl;
    __syncthreads();
    for (int i = t; i < cnt; i += 512) {
        int2 p = pb[i];
        int dl = (p.x >> 17) & 255;
        int pos = atomicAdd(&cur[dl], 1);
        ev[(size_t)gbase + pos] = make_int2(p.x & 0x1FFFF, p.y);
        atomicAdd(&wd[dl], (int)(__int_as_float(p.y) * WDSCALE + 0.5f));
    }
    __syncthreads();
    if (t < 256) {
        int g = (b << BSHIFT) + t;
        if (g < n) {
            dinv[g] = rsqrtf(1.f + (float)wd[t] * (1.f / WDSCALE));
            rp[g] = gbase + excl;
        }
    }
}

// gather: one wave per node, 8-deep ILP (round-14 version, 76us)
__global__ __launch_bounds__(256) void gather_bf(
    const int* __restrict__ rp, const int2* __restrict__ ev,
    const unsigned short* __restrict__ h,
    const float* __restrict__ dinv, const float* __restrict__ bias,
    unsigned short* __restrict__ aggr, int n) {
    int node = (int)(((size_t)blockIdx.x * 256 + threadIdx.x) >> 6);
    if (node >= n) return;
    int lane = threadIdx.x & 63;
    float di = dinv[node];
    float sl = di * di;
    unsigned int hu = *(const unsigned int*)(h + (size_t)node * 128 + lane * 2);
    float2 bv = *(const float2*)(bias + lane * 2);
    float ax0 = 0.f, ay0 = 0.f, ax1 = 0.f, ay1 = 0.f;
    float ax2 = 0.f, ay2 = 0.f, ax3 = 0.f, ay3 = 0.f;
    const int beg = rp[node], end = rp[node + 1];
    int i = beg;
    for (; i + 7 < end; i += 8) {
        int2 e[8];
#pragma unroll
        for (int j = 0; j < 8; ++j) e[j] = ev[i + j];
        float nm[8];
#pragma unroll
        for (int j = 0; j < 8; ++j) nm[j] = dinv[e[j].x] * __int_as_float(e[j].y);
        unsigned int u[8];
#pragma unroll
        for (int j = 0; j < 8; ++j)
            u[j] = *(const unsigned int*)(h + (size_t)e[j].x * 128 + lane * 2);
        ax0 += nm[0] * bflo(u[0]); ay0 += nm[0] * bfhi(u[0]);
        ax1 += nm[1] * bflo(u[1]); ay1 += nm[1] * bfhi(u[1]);
        ax2 += nm[2] * bflo(u[2]); ay2 += nm[2] * bfhi(u[2]);
        ax3 += nm[3] * bflo(u[3]); ay3 += nm[3] * bfhi(u[3]);
        ax0 += nm[4] * bflo(u[4]); ay0 += nm[4] * bfhi(u[4]);
        ax1 += nm[5] * bflo(u[5]); ay1 += nm[5] * bfhi(u[5]);
        ax2 += nm[6] * bflo(u[6]); ay2 += nm[6] * bfhi(u[6]);
        ax3 += nm[7] * bflo(u[7]); ay3 += nm[7] * bfhi(u[7]);
    }
    for (; i + 3 < end; i += 4) {
        int2 e0 = ev[i], e1 = ev[i + 1], e2 = ev[i + 2], e3 = ev[i + 3];
        float n0 = dinv[e0.x] * __int_as_float(e0.y);
        float n1 = dinv[e1.x] * __int_as_float(e1.y);
        float n2 = dinv[e2.x] * __int_as_float(e2.y);
        float n3 = dinv[e3.x] * __int_as_float(e3.y);
        unsigned int u0 = *(const unsigned int*)(h + (size_t)e0.x * 128 + lane * 2);
        unsigned int u1 = *(const unsigned int*)(h + (size_t)e1.x * 128 + lane * 2);
        unsigned int u2 = *(const unsigned int*)(h + (size_t)e2.x * 128 + lane * 2);
        unsigned int u3 = *(const unsigned int*)(h + (size_t)e3.x * 128 + lane * 2);
        ax0 += n0 * bflo(u0); ay0 += n0 * bfhi(u0);
        ax1 += n1 * bflo(u1); ay1 += n1 * bfhi(u1);
        ax2 += n2 * bflo(u2); ay2 += n2 * bfhi(u2);
        ax3 += n3 * bflo(u3); ay3 += n3 * bfhi(u3);
    }
    for (; i < end; ++i) {
        int2 e0 = ev[i];
        float n0 = dinv[e0.x] * __int_as_float(e0.y);
        unsigned int u0 = *(const unsigned int*)(h + (size_t)e0.x * 128 + lane * 2);
        ax0 += n0 * bflo(u0); ay0 += n0 * bfhi(u0);
    }
    float ox = frelu(di * ((ax0 + ax1) + (ax2 + ax3)) + sl * bflo(hu) + bv.x);
    float oy = frelu(di * ((ay0 + ay1) + (ay2 + ay3)) + sl * bfhi(hu) + bv.y);
    unsigned int o = (unsigned int)f2bf(ox) | ((unsigned int)f2bf(oy) << 16);
    *(unsigned int*)(aggr + (size_t)node * 128 + lane * 2) = o;
}

// ---------------- conv GEMM ----------------
template<int K, int BN, int RELU, int EPI>
__global__ __launch_bounds__(256, 2) void gemm_bf(
    const unsigned short* __restrict__ A, const unsigned short* __restrict__ Wt,
    const float* __restrict__ bias, void* __restrict__ Cout,
    int M, int nrows, float* __restrict__ xs) {
    constexpr int BM = 128, BK = 64;
    constexpr int WN = BN / 2;
    constexpr int NF = WN / 16;
    static_assert(BN == 64 || BN == 128, "BN");
    __shared__ unsigned short As[BM][BK + 8];
    __shared__ unsigned short Bs[BN][BK + 8];

    const int tid  = threadIdx.x;
    const int wid  = tid >> 6;
    const int lane = tid & 63;
    const int wm   = (wid >> 1) * 64;
    const int wn   = (wid & 1) * WN;
    const int row0 = blockIdx.x * BM;
    const int col0 = blockIdx.y * BN;
    const int lr   = lane & 15;
    const int lk   = (lane >> 4) * 8;

    f32x4 acc[4][NF] = {};

    for (int k0 = 0; k0 < K; k0 += BK) {
#pragma unroll
        for (int it = 0; it < 4; ++it) {
            int f = tid + it * 256;
            int r = f >> 3, g = f & 7;
            int grow = row0 + r;
            if (grow >= nrows) grow = nrows - 1;
            bf16x8 v = *(const bf16x8*)(A + (size_t)grow * K + k0 + g * 8);
            *(bf16x8*)&As[r][g * 8] = v;
        }
#pragma unroll
        for (int it = 0; it < BN / 32; ++it) {
            int f = tid + it * 256;
            int nidx = f >> 3, g = f & 7;
            bf16x8 v = *(const bf16x8*)(Wt + (size_t)(col0 + nidx) * K + k0 + g * 8);
            *(bf16x8*)&Bs[nidx][g * 8] = v;
        }
        __syncthreads();
#pragma unroll
        for (int kk = 0; kk < 2; ++kk) {
            bf16x8 af[4], bfv[NF];
#pragma unroll
            for (int mi = 0; mi < 4; ++mi)
                af[mi] = *(const bf16x8*)&As[wm + 16 * mi + lr][kk * 32 + lk];
#pragma unroll
            for (int ni = 0; ni < NF; ++ni)
                bfv[ni] = *(const bf16x8*)&Bs[wn + 16 * ni + lr][kk * 32 + lk];
#pragma unroll
            for (int mi = 0; mi < 4; ++mi)
#pragma unroll
                for (int ni = 0; ni < NF; ++ni)
                    acc[mi][ni] = __builtin_amdgcn_mfma_f32_16x16x32_bf16(
                        af[mi], bfv[ni], acc[mi][ni], 0, 0, 0);
        }
        __syncthreads();
    }

    const int dr0 = (lane >> 4) * 4;
#pragma unroll
    for (int ni = 0; ni < NF; ++ni) {
        int col = col0 + wn + 16 * ni + lr;
        float bv = bias ? bias[col] : 0.f;
#pragma unroll
        for (int mi = 0; mi < 4; ++mi) {
#pragma unroll
            for (int r = 0; r < 4; ++r) {
                int grow = row0 + wm + 16 * mi + dr0 + r;
                if (grow >= nrows) continue;
                float v = acc[mi][ni][r] + bv;
                if (RELU) v = frelu(v);
                if (EPI == 0) {
                    ((unsigned short*)Cout)[(size_t)grow * M + col] = f2bf(v);
                } else {
                    ((float*)Cout)[(size_t)grow * M + col] = v;
                    if (EPI == 2) xs[(size_t)grow * 64 + col] += v;
                }
            }
        }
    }
}

// ---------------- fused fc chain: in[128] ->256 ->128 ->64 ----------------
template<int EPI>
__global__ __launch_bounds__(256, 2) void fc_chain(
    const unsigned short* __restrict__ A,
    const unsigned short* __restrict__ W1t, const float* __restrict__ b1,
    const unsigned short* __restrict__ W2t, const float* __restrict__ b2,
    const unsigned short* __restrict__ W3t, const float* __restrict__ b3,
    float* __restrict__ Cout, int nrows, float* __restrict__ xs) {
    __shared__ unsigned short Ain[128 * 136];
    __shared__ unsigned short T1q[128 * 72];
    __shared__ unsigned short Bst[128 * 72];

    const int tid  = threadIdx.x;
    const int wid  = tid >> 6;
    const int lane = tid & 63;
    const int wm   = (wid >> 1) * 64;
    const int wnH  = (wid & 1) * 32;
    const int wnF  = (wid & 1) * 64;
    const int row0 = blockIdx.x * 128;
    const int lr   = lane & 15;
    const int lk   = (lane >> 4) * 8;
    const int dr0  = (lane >> 4) * 4;

#pragma unroll
    for (int it = 0; it < 8; ++it) {
        int f = tid + it * 256;
        int r = f >> 4, g = f & 15;
        int grow = row0 + r; if (grow >= nrows) grow = nrows - 1;
        *(bf16x8*)&Ain[r * 136 + g * 8] =
            *(const bf16x8*)(A + (size_t)grow * 128 + g * 8);
    }

    f32x4 acc2[4][4] = {};

    for (int q = 0; q < 4; ++q) {
        __syncthreads();
#pragma unroll
        for (int it = 0; it < 4; ++it) {
            int f = tid + it * 256;
            int r = f >> 4, g = f & 15;
            *(bf16x8*)&Bst[r * 136 + g * 8] =
                *(const bf16x8*)(W1t + (size_t)(q * 64 + r) * 128 + g * 8);
        }
        __syncthreads();
        f32x4 acc1[4][2] = {};
#pragma unroll
        for (int kk = 0; kk < 4; ++kk) {
            bf16x8 af[4], bw[2];
#pragma unroll
            for (int mi = 0; mi < 4; ++mi)
                af[mi] = *(const bf16x8*)&Ain[(wm + 16 * mi + lr) * 136 + kk * 32 + lk];
#pragma unroll
            for (int ni = 0; ni < 2; ++ni)
                bw[ni] = *(const bf16x8*)&Bst[(wnH + 16 * ni + lr) * 136 + kk * 32 + lk];
#pragma unroll
            for (int mi = 0; mi < 4; ++mi)
#pragma unroll
                for (int ni = 0; ni < 2; ++ni)
                    acc1[mi][ni] = __builtin_amdgcn_mfma_f32_16x16x32_bf16(
                        af[mi], bw[ni], acc1[mi][ni], 0, 0, 0);
        }
        __syncthreads();
#pragma unroll
        for (int ni = 0; ni < 2; ++ni) {
            float bv = b1[q * 64 + wnH + 16 * ni + lr];
#pragma unroll
            for (int mi = 0; mi < 4; ++mi)
#pragma unroll
                for (int r = 0; r < 4; ++r)
                    T1q[(wm + 16 * mi + dr0 + r) * 72 + wnH + 16 * ni + lr] =
                        f2bf(frelu(acc1[mi][ni][r] + bv));
        }
#pragma unroll
        for (int it = 0; it < 4; ++it) {
            int f = tid + it * 256;
            int r = f >> 3, g = f & 7;
            *(bf16x8*)&Bst[r * 72 + g * 8] =
                *(const bf16x8*)(W2t + (size_t)r * 256 + q * 64 + g * 8);
        }
        __syncthreads();
#pragma unroll
        for (int kk = 0; kk < 2; ++kk) {
            bf16x8 af[4], bw[4];
#pragma unroll
            for (int mi = 0; mi < 4; ++mi)
                af[mi] = *(const bf16x8*)&T1q[(wm + 16 * mi + lr) * 72 + kk * 32 + lk];
#pragma unroll
            for (int ni = 0; ni < 4; ++ni)
                bw[ni] = *(const bf16x8*)&Bst[(wnF + 16 * ni + lr) * 72 + kk * 32 + lk];
#pragma unroll
            for (int mi = 0; mi < 4; ++mi)
#pragma unroll
                for (int ni = 0; ni < 4; ++ni)
                    acc2[mi][ni] = __builtin_amdgcn_mfma_f32_16x16x32_bf16(
                        af[mi], bw[ni], acc2[mi][ni], 0, 0, 0);
        }
    }
    __syncthreads();
#pragma unroll
    for (int ni = 0; ni < 4; ++ni) {
        float bv = b2[wnF + 16 * ni + lr];
#pragma unroll
        for (int mi = 0; mi < 4; ++mi)
#pragma unroll
            for (int r = 0; r < 4; ++r)
                Ain[(wm + 16 * mi + dr0 + r) * 136 + wnF + 16 * ni + lr] =
                    f2bf(frelu(acc2[mi][ni][r] + bv));
    }
#pragma unroll
    for (int it = 0; it < 4; ++it) {
        int f = tid + it * 256;
        int r = f >> 4, g = f & 15;
        *(bf16x8*)&Bst[r * 136 + g * 8] =
            *(const bf16x8*)(W3t + (size_t)r * 128 + g * 8);
    }
    __syncthreads();
    f32x4 acc3[4][2] = {};
#pragma unroll
    for (int kk = 0; kk < 4; ++kk) {
        bf16x8 af[4], bw[2];
#pragma unroll
        for (int mi = 0; mi < 4; ++mi)
            af[mi] = *(const bf16x8*)&Ain[(wm + 16 * mi + lr) * 136 + kk * 32 + lk];
#pragma unroll
        for (int ni = 0; ni < 2; ++ni)
            bw[ni] = *(const bf16x8*)&Bst[(wnH + 16 * ni + lr) * 136 + kk * 32 + lk];
#pragma unroll
        for (int mi = 0; mi < 4; ++mi)
#pragma unroll
            for (int ni = 0; ni < 2; ++ni)
                acc3[mi][ni] = __builtin_amdgcn_mfma_f32_16x16x32_bf16(
                    af[mi], bw[ni], acc3[mi][ni], 0, 0, 0);
    }
#pragma unroll
    for (int ni = 0; ni < 2; ++ni) {
        int col = wnH + 16 * ni + lr;
        float bv = b3[col];
#pragma unroll
        for (int mi = 0; mi < 4; ++mi)
#pragma unroll
            for (int r = 0; r < 4; ++r) {
                int grow = row0 + wm + 16 * mi + dr0 + r;
                if (grow >= nrows) continue;
                float v = frelu(acc3[mi][ni][r] + bv);
                Cout[(size_t)grow * 64 + col] = v;
                if (EPI == 2) xs[(size_t)grow * 64 + col] += v;
            }
    }
}

// ---------------------------------------------------------------------------
extern "C" void kernel_launch(void* const* d_in, const int* in_sizes, int n_in,
                              void* d_out, int out_size, void* d_ws, size_t ws_size,
                              hipStream_t stream) {
    (void)n_in; (void)out_size; (void)ws_size;
    const float* X = (const float*)d_in[0];
    const int N = in_sizes[0] / 128;

    const float* fc1_b1 = (const float*)d_in[20];
    const float* fc1_b2 = (const float*)d_in[22];
    const float* fc1_b3 = (const float*)d_in[24];
    const float* fc2_b1 = (const float*)d_in[26];
    const float* fc2_b2 = (const float*)d_in[28];
    const float* fc2_b3 = (const float*)d_in[30];

    float* out = (float*)d_out;
    float* Xs  = out;  // slot 0

    // ---- workspace layout ----
    char* base = (char*)d_ws;
    const size_t Npad = (((size_t)N + 255) / 256) * 256;
    float*          dinv  = (float*)base;                 base += Npad * 4;
    unsigned short* Xbf   = (unsigned short*)base;        base += (size_t)N * 128 * 2;
    unsigned short* t1bf  = (unsigned short*)base;        base += (size_t)N * 256 * 2;  // CSR arena
    unsigned short* t2bf  = (unsigned short*)base;        base += (size_t)N * 128 * 2;
    unsigned short* aggbf = (unsigned short*)base;        base += (size_t)N * 128 * 2;
    unsigned short* wtbuf = (unsigned short*)base;        base += 245760 * 2;
    int*            gcur3 = (int*)base;                   base += 3 * NBUCK_MAX * 4;
    int*            bbase = (int*)base;                   base += NBUCK_MAX * 4;

    unsigned short* fc1w1t = wtbuf;
    unsigned short* fc1w2t = fc1w1t + 32768;
    unsigned short* fc1w3t = fc1w2t + 32768;
    unsigned short* fc2w1t = fc1w3t + 8192;
    unsigned short* fc2w2t = fc2w1t + 32768;
    unsigned short* fc2w3t = fc2w2t + 32768;
    unsigned short* gwt    = fc2w3t + 8192;        // 6 x 16384

    const dim3 blk(256);
    const int GR = (N + 127) / 128;
    const int NBUCK = (N + 255) >> 8;     // 391 for N=100000
    const int GWB = (int)(((size_t)N * 64 + 255) / 256);

    // ---- one-time conversions (batched) ----
    xconv<<<(N * 32 + 255) / 256, blk, 0, stream>>>(X, Xbf, N * 32);
    {
        WSegs segs;
        const float* srcs[13] = {
            (const float*)d_in[19], (const float*)d_in[21], (const float*)d_in[23],
            (const float*)d_in[25], (const float*)d_in[27], (const float*)d_in[29],
            (const float*)d_in[3],  (const float*)d_in[5],
            (const float*)d_in[9],  (const float*)d_in[11],
            (const float*)d_in[15], (const float*)d_in[17]
        };
        unsigned short* dsts[13] = {
            fc1w1t, fc1w2t, fc1w3t, fc2w1t, fc2w2t, fc2w3t,
            gwt, gwt + 16384, gwt + 32768, gwt + 49152, gwt + 65536, gwt + 81920
        };
        int ksh[13] = {7, 8, 7, 7, 8, 7, 7, 7, 7, 7, 7, 7};
        int Ms[13]  = {256, 128, 64, 256, 128, 64, 128, 128, 128, 128, 128, 128};
        int sz[13]  = {32768, 32768, 8192, 32768, 32768, 8192,
                       16384, 16384, 16384, 16384, 16384, 16384};
        int acc = 0;
        for (int i = 0; i < 12; ++i) {
            segs.src[i] = srcs[i]; segs.dst[i] = dsts[i];
            segs.ksh[i] = ksh[i];  segs.M[i] = Ms[i];
            segs.beg[i] = acc;     acc += sz[i];
        }
        segs.src[12] = srcs[11]; segs.dst[12] = dsts[11];
        segs.ksh[12] = 7; segs.M[12] = 128;
        segs.beg[12] = acc; segs.beg[13] = acc;
        wtrans_all<<<(acc + 255) / 256, blk, 0, stream>>>(segs, acc);
    }
    zero_small<<<(3 * NBUCK_MAX + 255) / 256, blk, 0, stream>>>(gcur3, 3 * NBUCK_MAX);

    // ---- X0 = fc1(X) -> Xs (fused chain) ----
    fc_chain<1><<<GR, blk, 0, stream>>>(Xbf, fc1w1t, fc1_b1, fc1w2t, fc1_b2,
                                        fc1w3t, fc1_b3, Xs, N, nullptr);

    // ---- graphs ----
    for (int g = 0; g < 3; ++g) {
        const int*   ei  = (const int*)d_in[1 + 6 * g];
        const int    E   = in_sizes[1 + 6 * g] / 2;
        const int*   srp = ei;
        const int*   dsp = ei + E;
        const float* ew  = (const float*)d_in[2 + 6 * g];
        const float* b1  = (const float*)d_in[4 + 6 * g];
        const float* b2  = (const float*)d_in[6 + 6 * g];
        unsigned short* w1t = gwt + (size_t)g * 32768;
        unsigned short* w2t = w1t + 16384;
        int* gcur = gcur3 + g * NBUCK_MAX;

        // CSR arena aliases t1bf
        int2* part  = (int2*)t1bf;                        // NBUCK * BCAP
        int2* ev    = part + (size_t)NBUCK * BCAP;        // E
        int*  rpn   = (int*)(ev + E);                     // N+1

        part_k<<<(E + 4095) / 4096, blk, 0, stream>>>(srp, dsp, ew, gcur, part, E, NBUCK);
        scanB<<<1, 512, 0, stream>>>(gcur, bbase, rpn, N, NBUCK);
        csr_bucket<<<NBUCK, 512, 0, stream>>>(part, gcur, bbase, ev, rpn, dinv, N);

        // conv1 + conv2
        gemm_bf<128, 128, 0, 0><<<dim3(GR, 1), blk, 0, stream>>>(Xbf, w1t, nullptr, t2bf, 128, N, nullptr);
        gather_bf<<<GWB, blk, 0, stream>>>(rpn, ev, t2bf, dinv, b1, aggbf, N);
        gemm_bf<128, 128, 0, 0><<<dim3(GR, 1), blk, 0, stream>>>(aggbf, w2t, nullptr, t2bf, 128, N, nullptr);
        gather_bf<<<GWB, blk, 0, stream>>>(rpn, ev, t2bf, dinv, b2, aggbf, N);

        // fc2 head (fused chain, xs accumulate)
        fc_chain<2><<<GR, blk, 0, stream>>>(aggbf, fc2w1t, fc2_b1, fc2w2t, fc2_b2,
                                            fc2w3t, fc2_b3,
                                            out + (size_t)(1 + g) * N * 64, N, Xs);
    }
}